// Round 9
// baseline (4162.648 us; speedup 1.0000x reference)
//
#include <hip/hip_runtime.h>

// Quantum-LSTM forward. 512 blocks x 4 waves, 1 sample/block. Round-9:
// R2's coefficient mechanism (make_K merged-pair per-lane K, allocator left
// alone -- best measured, 620us) + serial-path/sync fixes:
//  1. ONE barrier/step: all waves redundantly compute the h-circuit (wave 1
//     also y, ILP-2); h stays in registers via readlane from the 6 Walsh
//     lanes. gates4 double-buffered (WAR across steps).
//  2. Gather-free expvals: FWHT leaves <Z_w> at lanes {2A,15,01,35,3A,3D};
//     those lanes publish/read directly (gidx). Removes 2 ds_bpermute from
//     the critical path per step.
//  3. Tree embedding (depth 3), reassociated gate stage (depth halved),
//     verified-DPP shuffles for masks {1,2,3,4,5,7,8,A,C,F}.

namespace {

constexpr int BATCH  = 512;
constexpr int TSTEPS = 256;

typedef float v2f __attribute__((ext_vector_type(2)));

__device__ __forceinline__ v2f splat2(float s) { v2f r; r.x = s; r.y = s; return r; }
__device__ __forceinline__ v2f cswapneg(v2f v) { v2f r; r.x = -v.y; r.y = v.x; return r; }
__device__ __forceinline__ v2f cmul(v2f a, v2f b) {
  v2f r; r.x = fmaf(a.x, b.x, -(a.y * b.y)); r.y = fmaf(a.x, b.y, a.y * b.x); return r;
}

__device__ __forceinline__ float sigf(float v) { return 1.0f / (1.0f + __expf(-v)); }
__device__ __forceinline__ float tanh_fast(float v) { return 1.0f - 2.0f / (1.0f + __expf(v + v)); }

__device__ __forceinline__ float rl(float v, int l) {
  return __int_as_float(__builtin_amdgcn_readlane(__float_as_int(v), l));
}

template<int CTRL>
__device__ __forceinline__ float dppmov(float v) {
  return __int_as_float(__builtin_amdgcn_mov_dpp(__float_as_int(v), CTRL, 0xF, 0xF, true));
}
// Verified (R4-R7 passing): quad_perm xor1=0xB1 xor2=0x4E xor3=0x1B;
// half_mirror=0x141 (xor7), row_ror:8=0x128 (xor8), row_mirror=0x140 (xorF).

template<int M>
__device__ __forceinline__ float shx(float v, int lane4) {
  if constexpr      (M == 0x01) return dppmov<0xB1>(v);
  else if constexpr (M == 0x02) return dppmov<0x4E>(v);
  else if constexpr (M == 0x03) return dppmov<0x1B>(v);
  else if constexpr (M == 0x04) return dppmov<0x1B>(dppmov<0x141>(v));
  else if constexpr (M == 0x05) return dppmov<0x4E>(dppmov<0x141>(v));
  else if constexpr (M == 0x07) return dppmov<0x141>(v);
  else if constexpr (M == 0x08) return dppmov<0x128>(v);
  else if constexpr (M == 0x0A) return dppmov<0x4E>(dppmov<0x128>(v));
  else if constexpr (M == 0x0C) return dppmov<0x1B>(dppmov<0x140>(v));
  else if constexpr (M == 0x0F) return dppmov<0x140>(v);
  else if constexpr (M < 32) {
    return __int_as_float(__builtin_amdgcn_ds_swizzle(__float_as_int(v), 0x1F | (M << 10)));
  } else {
    return __int_as_float(__builtin_amdgcn_ds_bpermute(lane4 ^ (M << 2), __float_as_int(v)));
  }
}

// merged-pair stage, reassociated: u = ((K0 s + K1 s^M1) + (K2 s^M2 + K3 s^M12))
template<int M1, int M2, int M12>
__device__ __forceinline__ void stage1f(v2f& s, float4 kA, float4 kB, int lane4) {
  v2f v1, v2, v3;
  v1.x = shx<M1>(s.x, lane4);  v1.y = shx<M1>(s.y, lane4);
  v2.x = shx<M2>(s.x, lane4);  v2.y = shx<M2>(s.y, lane4);
  v3.x = shx<M12>(s.x, lane4); v3.y = shx<M12>(s.y, lane4);
  v2f t0 = splat2(kA.x) * s;  t0 = __builtin_elementwise_fma(splat2(kA.y), cswapneg(s),  t0);
  v2f t1 = splat2(kA.z) * v1; t1 = __builtin_elementwise_fma(splat2(kA.w), cswapneg(v1), t1);
  v2f t2 = splat2(kB.x) * v2; t2 = __builtin_elementwise_fma(splat2(kB.y), cswapneg(v2), t2);
  v2f t3 = splat2(kB.z) * v3; t3 = __builtin_elementwise_fma(splat2(kB.w), cswapneg(v3), t3);
  s = (t0 + t1) + (t2 + t3);
}

// two independent states (h and y circuits), shuffles batched first
template<int M1, int M2, int M12>
__device__ __forceinline__ void stage2f(v2f& sa, float4 kAa, float4 kBa,
                                        v2f& sb, float4 kAb, float4 kBb, int lane4) {
  v2f a1, a2, a3, b1, b2, b3;
  a1.x = shx<M1>(sa.x, lane4);  a1.y = shx<M1>(sa.y, lane4);
  b1.x = shx<M1>(sb.x, lane4);  b1.y = shx<M1>(sb.y, lane4);
  a2.x = shx<M2>(sa.x, lane4);  a2.y = shx<M2>(sa.y, lane4);
  b2.x = shx<M2>(sb.x, lane4);  b2.y = shx<M2>(sb.y, lane4);
  a3.x = shx<M12>(sa.x, lane4); a3.y = shx<M12>(sa.y, lane4);
  b3.x = shx<M12>(sb.x, lane4); b3.y = shx<M12>(sb.y, lane4);
  v2f t0 = splat2(kAa.x) * sa; t0 = __builtin_elementwise_fma(splat2(kAa.y), cswapneg(sa), t0);
  v2f t1 = splat2(kAa.z) * a1; t1 = __builtin_elementwise_fma(splat2(kAa.w), cswapneg(a1), t1);
  v2f t2 = splat2(kBa.x) * a2; t2 = __builtin_elementwise_fma(splat2(kBa.y), cswapneg(a2), t2);
  v2f t3 = splat2(kBa.z) * a3; t3 = __builtin_elementwise_fma(splat2(kBa.w), cswapneg(a3), t3);
  sa = (t0 + t1) + (t2 + t3);
  v2f u0 = splat2(kAb.x) * sb; u0 = __builtin_elementwise_fma(splat2(kAb.y), cswapneg(sb), u0);
  v2f u1 = splat2(kAb.z) * b1; u1 = __builtin_elementwise_fma(splat2(kAb.w), cswapneg(b1), u1);
  v2f u2 = splat2(kBb.x) * b2; u2 = __builtin_elementwise_fma(splat2(kBb.y), cswapneg(b2), u2);
  v2f u3 = splat2(kBb.z) * b3; u3 = __builtin_elementwise_fma(splat2(kBb.w), cswapneg(b3), u3);
  sb = (u0 + u1) + (u2 + u3);
}

__device__ __forceinline__ void chain1(v2f& s, const float4 (&kA)[6],
                                       const float4 (&kB)[6], int lane4) {
  stage1f<0x0F,0x1E,0x11>(s, kA[0], kB[0], lane4);
  stage1f<0x3C,0x3B,0x07>(s, kA[1], kB[1], lane4);
  stage1f<0x3F,0x3D,0x02>(s, kA[2], kB[2], lane4);
  stage1f<0x16,0x26,0x30>(s, kA[3], kB[3], lane4);
  stage1f<0x05,0x28,0x2D>(s, kA[4], kB[4], lane4);
  stage1f<0x14,0x0A,0x1E>(s, kA[5], kB[5], lane4);
}

__device__ __forceinline__ void chain2(v2f& sa, const float4 (&kAa)[6], const float4 (&kBa)[6],
                                       v2f& sb, const float4 (&kAb)[6], const float4 (&kBb)[6],
                                       int lane4) {
  stage2f<0x0F,0x1E,0x11>(sa, kAa[0], kBa[0], sb, kAb[0], kBb[0], lane4);
  stage2f<0x3C,0x3B,0x07>(sa, kAa[1], kBa[1], sb, kAb[1], kBb[1], lane4);
  stage2f<0x3F,0x3D,0x02>(sa, kAa[2], kBa[2], sb, kAb[2], kBb[2], lane4);
  stage2f<0x16,0x26,0x30>(sa, kAa[3], kBa[3], sb, kAb[3], kBb[3], lane4);
  stage2f<0x05,0x28,0x2D>(sa, kAa[4], kBa[4], sb, kAb[4], kBb[4], lane4);
  stage2f<0x14,0x0A,0x1E>(sa, kAa[5], kBa[5], sb, kAb[5], kBb[5], lane4);
}

// merged FWHT, NO gather: result at lane L is the Walsh coeff of row L;
// lanes {0x2A,0x15,0x01,0x35,0x3A,0x3D} hold <Z_0..Z_5>.
__device__ __forceinline__ float expv(v2f s, const float (&fs)[9], int lane4) {
  float p  = fmaf(s.x, s.x, s.y * s.y);
  float pa = shx<1>(p, lane4), pb = shx<2>(p, lane4), pc = shx<3>(p, lane4);
  p = fmaf(fs[0], p, fmaf(fs[1], pa, fmaf(fs[2], pb, pc)));
  pa = shx<4>(p, lane4); pb = shx<8>(p, lane4); pc = shx<12>(p, lane4);
  p = fmaf(fs[3], p, fmaf(fs[4], pa, fmaf(fs[5], pb, pc)));
  pa = shx<16>(p, lane4); pb = shx<32>(p, lane4); pc = shx<48>(p, lane4);
  p = fmaf(fs[6], p, fmaf(fs[7], pa, fmaf(fs[8], pb, pc)));
  return p;
}

// half-angle products for wire value Xv: A=c1c2 B=c1s2 C=s1c2 D=s1s2
__device__ __forceinline__ void trig(float Xv, float& A_, float& B_, float& C_, float& D_) {
  float tq   = Xv * Xv;
  float cth1 = rsqrtf(1.f + tq);
  float sth1 = Xv * cth1;
  float u1   = 1.f + cth1, r1 = rsqrtf(u1 + u1);
  float c1   = u1 * r1,    s1 = sth1 * r1;
  float tq2  = tq * tq;
  float cth2 = rsqrtf(1.f + tq2);
  float sth2 = tq * cth2;
  float u2   = 1.f + cth2, r2 = rsqrtf(u2 + u2);
  float c2   = u2 * r2,    s2 = sth2 * r2;
  A_ = c1 * c2; B_ = c1 * s2; C_ = s1 * c2; D_ = s1 * s2;
}

// Walsh-lane owners of wires 0..5 (rows of M2, verified since R1)
__device__ __constant__ int LW_[1]; // (placeholder to keep constants local)

// product-state embedding, tree-shaped (depth 3); wire w broadcast from its
// Walsh lane. Factor math identical to the verified embed_rl.
__device__ __forceinline__ v2f embed_tree(float A_, float B_, float C_, float D_, int lane) {
  constexpr int LW[6] = {0x2A, 0x15, 0x01, 0x35, 0x3A, 0x3D};
  v2f f[6];
#pragma unroll
  for (int w = 0; w < 6; ++w) {
    float Aj = rl(A_, LW[w]), Bj = rl(B_, LW[w]);
    float Cj = rl(C_, LW[w]), Dj = rl(D_, LW[w]);
    bool bj = (lane >> w) & 1;
    f[w].x = bj ? Cj : Aj;
    f[w].y = bj ? Dj : -Bj;
  }
  v2f p01 = cmul(f[0], f[1]);
  v2f p23 = cmul(f[2], f[3]);
  v2f p45 = cmul(f[4], f[5]);
  return cmul(cmul(p01, p23), p45);
}

// per-lane merged-pair coefficients for one circuit (R2 exact, best measured)
__device__ __forceinline__ void make_K(const float4* fgc, int lane,
                                       float4 (&kA)[6], float4 (&kB)[6]) {
  constexpr unsigned BM[2][6] = {
    {0x18,0x30,0x39,0x0C,0x26,0x33},
    {0x2A,0x15,0x01,0x35,0x3A,0x3D}};
#pragma unroll
  for (int s = 0; s < 6; ++s) {
    int l = s / 3, i0 = (s % 3) * 2;
    float4 ga1 = fgc[(l*6+i0)*2],     gb1 = fgc[(l*6+i0)*2+1];
    float4 ga2 = fgc[(l*6+i0+1)*2],   gb2 = fgc[(l*6+i0+1)*2+1];
    bool p1 = __popc(lane & (int)BM[l][i0])   & 1;
    bool p2 = __popc(lane & (int)BM[l][i0+1]) & 1;
    float arr = p1 ? gb1.z : ga1.x, ari = p1 ? gb1.w : ga1.y;
    float brr = p1 ? gb1.x : ga1.z, bri = p1 ? gb1.y : ga1.w;
    float crr = p2 ? gb2.z : ga2.x, cri = p2 ? gb2.w : ga2.y;
    float drr = p2 ? gb2.x : ga2.z, dri = p2 ? gb2.y : ga2.w;
    kA[s] = make_float4(crr*arr - cri*ari, crr*ari + cri*arr,
                        crr*brr - cri*bri, crr*bri + cri*brr);
    kB[s] = make_float4(drr*arr - dri*ari, drr*ari + dri*arr,
                        drr*brr - dri*bri, drr*bri + dri*brr);
  }
}

} // namespace

__global__ __launch_bounds__(256, 2)
void qlstm_kernel(const float* __restrict__ x, const float* __restrict__ phi,
                  const float* __restrict__ Wc, const float* __restrict__ bc,
                  float* __restrict__ out)
{
  __shared__ float4 fG[144];        // 6 circuits x 12 gates x {row0, row1}
  __shared__ float4 gates4[2][6];   // double-buffered (f,i,C,o) per wire

  const int tid   = threadIdx.x;
  const int wave  = tid >> 6;
  const int lane  = tid & 63;
  const int lane4 = lane << 2;
  const int b     = blockIdx.x;

  // ---- one-time: fused gate matrices (R2 exact) ----
  if (tid < 72) {
    int g = tid / 12, rem = tid % 12, l = rem / 6, i = rem % 6;
    const float* w = phi + g*36 + l*18 + i*3;
    float sa, ca, sb, cb, sc, cc;
    sincosf(0.5f * w[0], &sa, &ca);
    sincosf(0.5f * w[1], &sb, &cb);
    sincosf(0.5f * w[2], &sc, &cc);
    float m00r =  cb*ca, m00i =  sb*sa;
    float m01r = -sb*ca, m01i = -cb*sa;
    float m10r =  sb*ca, m10i = -cb*sa;
    float m11r =  cb*ca, m11i = -sb*sa;
    float4 A, Bv;
    A.x  = m00r*cc + m00i*sc;  A.y  = m00i*cc - m00r*sc;
    A.z  = m01r*cc + m01i*sc;  A.w  = m01i*cc - m01r*sc;
    Bv.x = m10r*cc - m10i*sc;  Bv.y = m10i*cc + m10r*sc;
    Bv.z = m11r*cc - m11i*sc;  Bv.w = m11i*cc + m11r*sc;
    fG[2*tid] = A; fG[2*tid+1] = Bv;
  }
  __syncthreads();

  // ---- per-lane loop-invariants ----
  // gidx: wire owned by this lane's Walsh coefficient (-1 if none)
  const int gidx = (lane == 0x2A) ? 0 : (lane == 0x15) ? 1 : (lane == 0x01) ? 2 :
                   (lane == 0x35) ? 3 : (lane == 0x3A) ? 4 : (lane == 0x3D) ? 5 : -1;
  const int jrow = (gidx >= 0) ? gidx : 0;

  float Wr[14];
#pragma unroll
  for (int k = 0; k < 14; ++k) Wr[k] = Wc[jrow*14 + k];
  const float bcj = bc[jrow];

  float sgn[6];
#pragma unroll
  for (int k = 0; k < 6; ++k) sgn[k] = ((lane >> k) & 1) ? -1.f : 1.f;
  float fs[9] = { sgn[0]*sgn[1], sgn[1], sgn[0],
                  sgn[2]*sgn[3], sgn[3], sgn[2],
                  sgn[4]*sgn[5], sgn[5], sgn[4] };

  // coefficient sets: own phase-1 circuit; h-circuit (4) for ALL waves;
  // wave 1 additionally y-circuit (5)
  float4 kA1[6], kB1[6], kA4[6], kB4[6], kA5[6], kB5[6];
  make_K(&fG[wave * 24], lane, kA1, kB1);
  make_K(&fG[4 * 24],    lane, kA4, kB4);
  if (wave == 1) make_K(&fG[5 * 24], lane, kA5, kB5);

  float c_sc = 0.f;   // cell state, meaningful at gidx lanes
  float p2   = 0.f;   // h-circuit Walsh result (h at gidx lanes), h0 = 0

  const float* xbase = x + (size_t)b * TSTEPS * 8;
  float4 xa = *(const float4*)(xbase);
  float4 xb = *(const float4*)(xbase + 4);

  for (int t = 0; t < TSTEPS; ++t) {
    // ---- X at all lanes (meaningful at gidx lanes); h via readlane ----
    float h0 = rl(p2, 0x2A), h1 = rl(p2, 0x15), h2 = rl(p2, 0x01);
    float h3 = rl(p2, 0x35), h4 = rl(p2, 0x3A), h5 = rl(p2, 0x3D);
    float acc = bcj;
    acc = fmaf(xa.x, Wr[0],  acc); acc = fmaf(xa.y, Wr[1],  acc);
    acc = fmaf(xa.z, Wr[2],  acc); acc = fmaf(xa.w, Wr[3],  acc);
    acc = fmaf(xb.x, Wr[4],  acc); acc = fmaf(xb.y, Wr[5],  acc);
    acc = fmaf(xb.z, Wr[6],  acc); acc = fmaf(xb.w, Wr[7],  acc);
    acc = fmaf(h0,   Wr[8],  acc); acc = fmaf(h1,   Wr[9],  acc);
    acc = fmaf(h2,   Wr[10], acc); acc = fmaf(h3,   Wr[11], acc);
    acc = fmaf(h4,   Wr[12], acc); acc = fmaf(h5,   Wr[13], acc);
    float Xj = 1.f - 2.f / (1.f + __expf(acc));

    // prefetch next x
    int tn = (t + 1 < TSTEPS) ? (t + 1) : t;
    float4 xa_n = *(const float4*)(xbase + (size_t)tn * 8);
    float4 xb_n = *(const float4*)(xbase + (size_t)tn * 8 + 4);

    // ---- phase 1: embed (tree), own circuit, publish at Walsh lane ----
    float A_, B_, C_, D_;
    trig(Xj, A_, B_, C_, D_);
    v2f s = embed_tree(A_, B_, C_, D_, lane);
    chain1(s, kA1, kB1, lane4);
    float p   = expv(s, fs, lane4);
    float sgv = sigf(p);
    if (gidx >= 0) ((float*)&gates4[t & 1][gidx])[wave] = sgv;
    __syncthreads();   // the ONLY barrier per step

    // ---- phase 2: cell update + h (all waves); wave1 also y (ILP-2) ----
    float4 g4 = gates4[t & 1][jrow];
    float cn  = fmaf(g4.x, c_sc, g4.y * g4.z);
    c_sc = cn;
    float resc = g4.w * tanh_fast(cn);
    float A2, B2, C2, D2;
    trig(resc, A2, B2, C2, D2);
    v2f e2 = embed_tree(A2, B2, C2, D2, lane);
    if (wave == 1) {
      v2f sh = e2, sy = e2;
      chain2(sh, kA4, kB4, sy, kA5, kB5, lane4);
      p2 = expv(sh, fs, lane4);
      float py = expv(sy, fs, lane4);
      if (gidx >= 0) out[((size_t)b * TSTEPS + t) * 6 + gidx] = py;
    } else {
      v2f sh = e2;
      chain1(sh, kA4, kB4, lane4);
      p2 = expv(sh, fs, lane4);
    }
    xa = xa_n; xb = xb_n;
  }

  // ---- final c, h (wave 0, Walsh lanes) ----
  if (wave == 0 && gidx >= 0) {
    size_t cbase = (size_t)BATCH * TSTEPS * 6;
    out[cbase + (size_t)b * 6 + gidx] = c_sc;
    out[cbase + (size_t)BATCH * 6 + (size_t)b * 6 + gidx] = p2;
  }
}

extern "C" void kernel_launch(void* const* d_in, const int* in_sizes, int n_in,
                              void* d_out, int out_size, void* d_ws, size_t ws_size,
                              hipStream_t stream) {
  const float* x   = (const float*)d_in[0];
  const float* phi = (const float*)d_in[1];
  const float* Wc  = (const float*)d_in[2];
  const float* bc  = (const float*)d_in[3];
  float* out = (float*)d_out;
  (void)in_sizes; (void)n_in; (void)out_size; (void)d_ws; (void)ws_size;
  hipLaunchKernelGGL(qlstm_kernel, dim3(BATCH), dim3(256), 0, stream,
                     x, phi, Wc, bc, out);
}

// Round 10
// 679.559 us; speedup vs baseline: 6.1255x; 6.1255x over previous
//
#include <hip/hip_runtime.h>

// Quantum-LSTM forward. Round-10: coefficients move to the SGPR file.
// Structure = R2's 512x4-wave block layout (best measured, 620us) with:
//  1. Wave-uniform gate coefficients (SU(2) conj-neg row trick, R5-verified)
//     fused by a prep kernel into d_ws, then loaded ONCE per wave via
//     readfirstlane-forced s_load_dwordx4 -> ~96 SGPRs, resident across the
//     whole t-loop. Zero VGPR cost, zero DS ops, zero remat (R2-R9's
//     recurring 40%-of-VALU leak).
//  2. Un-merged 12-gate chain (R5-verified gate1: 2 shuffles + 2 xor +
//     8 fma per gate, scalar coeffs legal as 1-SGPR-read VALU operands).
//  3. Tree embedding + gather-free expvals + Walsh-lane (gidx) publish
//     (all R9-verified numerics).
// DPP set R4-verified; ds_swizzle (<32) / ds_bpermute (>=32) otherwise.

namespace {

constexpr int BATCH  = 512;
constexpr int TSTEPS = 256;

typedef float v2f __attribute__((ext_vector_type(2)));

__device__ __forceinline__ v2f splat2(float s) { v2f r; r.x = s; r.y = s; return r; }
__device__ __forceinline__ v2f cswapneg(v2f v) { v2f r; r.x = -v.y; r.y = v.x; return r; }
__device__ __forceinline__ v2f cmul(v2f a, v2f b) {
  v2f r; r.x = fmaf(a.x, b.x, -(a.y * b.y)); r.y = fmaf(a.x, b.y, a.y * b.x); return r;
}

__device__ __forceinline__ float sigf(float v) { return 1.0f / (1.0f + __expf(-v)); }
__device__ __forceinline__ float tanh_fast(float v) { return 1.0f - 2.0f / (1.0f + __expf(v + v)); }

__device__ __forceinline__ float rl(float v, int l) {
  return __int_as_float(__builtin_amdgcn_readlane(__float_as_int(v), l));
}

template<int CTRL>
__device__ __forceinline__ float dppmov(float v) {
  return __int_as_float(__builtin_amdgcn_mov_dpp(__float_as_int(v), CTRL, 0xF, 0xF, true));
}
// Verified (R4-R8 passing): quad_perm xor1=0xB1 xor2=0x4E xor3=0x1B;
// half_mirror=0x141 (xor7), row_ror:8=0x128 (xor8), row_mirror=0x140 (xorF).

template<int M>
__device__ __forceinline__ float shx(float v, int lane4) {
  if constexpr      (M == 0x01) return dppmov<0xB1>(v);
  else if constexpr (M == 0x02) return dppmov<0x4E>(v);
  else if constexpr (M == 0x03) return dppmov<0x1B>(v);
  else if constexpr (M == 0x04) return dppmov<0x1B>(dppmov<0x141>(v));
  else if constexpr (M == 0x05) return dppmov<0x4E>(dppmov<0x141>(v));
  else if constexpr (M == 0x07) return dppmov<0x141>(v);
  else if constexpr (M == 0x08) return dppmov<0x128>(v);
  else if constexpr (M == 0x0A) return dppmov<0x4E>(dppmov<0x128>(v));
  else if constexpr (M == 0x0C) return dppmov<0x1B>(dppmov<0x140>(v));
  else if constexpr (M == 0x0F) return dppmov<0x140>(v);
  else if constexpr (M < 32) {
    return __int_as_float(__builtin_amdgcn_ds_swizzle(__float_as_int(v), 0x1F | (M << 10)));
  } else {
    return __int_as_float(__builtin_amdgcn_ds_bpermute(lane4 ^ (M << 2), __float_as_int(v)));
  }
}

// one gate: WAVE-UNIFORM coeffs A=(G00r,G00i,G01r,G01i) (SGPR-resident),
// per-lane sign mask pm (0 / 0x80000000): row select == conj-neg (SU(2)).
// Verified R5/R8.
template<int M>
__device__ __forceinline__ void gate1(v2f& s, float4 A, int pm, int lane4) {
  v2f v; v.x = shx<M>(s.x, lane4); v.y = shx<M>(s.y, lane4);
  float sai = __int_as_float(__float_as_int(A.y) ^ pm);
  float sbr = __int_as_float(__float_as_int(A.z) ^ pm);
  v2f u = splat2(A.x) * s;
  u = __builtin_elementwise_fma(splat2(sai), cswapneg(s), u);
  u = __builtin_elementwise_fma(splat2(sbr), v,           u);
  u = __builtin_elementwise_fma(splat2(A.w), cswapneg(v), u);
  s = u;
}

__device__ __forceinline__ void chain12(v2f& s, const float4 (&K)[12],
                                        const int (&pm)[12], int lane4) {
  gate1<0x0F>(s, K[0],  pm[0],  lane4);
  gate1<0x1E>(s, K[1],  pm[1],  lane4);
  gate1<0x3C>(s, K[2],  pm[2],  lane4);
  gate1<0x3B>(s, K[3],  pm[3],  lane4);
  gate1<0x3F>(s, K[4],  pm[4],  lane4);
  gate1<0x3D>(s, K[5],  pm[5],  lane4);
  gate1<0x16>(s, K[6],  pm[6],  lane4);
  gate1<0x26>(s, K[7],  pm[7],  lane4);
  gate1<0x05>(s, K[8],  pm[8],  lane4);
  gate1<0x28>(s, K[9],  pm[9],  lane4);
  gate1<0x14>(s, K[10], pm[10], lane4);
  gate1<0x0A>(s, K[11], pm[11], lane4);
}

// merged FWHT, gather-free (R9-verified): lane L ends with Walsh coeff of
// row L; lanes {2A,15,01,35,3A,3D} hold <Z_0..Z_5>.
__device__ __forceinline__ float expv(v2f s, const float (&fs)[9], int lane4) {
  float p  = fmaf(s.x, s.x, s.y * s.y);
  float pa = shx<1>(p, lane4), pb = shx<2>(p, lane4), pc = shx<3>(p, lane4);
  p = fmaf(fs[0], p, fmaf(fs[1], pa, fmaf(fs[2], pb, pc)));
  pa = shx<4>(p, lane4); pb = shx<8>(p, lane4); pc = shx<12>(p, lane4);
  p = fmaf(fs[3], p, fmaf(fs[4], pa, fmaf(fs[5], pb, pc)));
  pa = shx<16>(p, lane4); pb = shx<32>(p, lane4); pc = shx<48>(p, lane4);
  p = fmaf(fs[6], p, fmaf(fs[7], pa, fmaf(fs[8], pb, pc)));
  return p;
}

// half-angle products for wire value Xv: A=c1c2 B=c1s2 C=s1c2 D=s1s2
__device__ __forceinline__ void trig(float Xv, float& A_, float& B_, float& C_, float& D_) {
  float tq   = Xv * Xv;
  float cth1 = rsqrtf(1.f + tq);
  float sth1 = Xv * cth1;
  float u1   = 1.f + cth1, r1 = rsqrtf(u1 + u1);
  float c1   = u1 * r1,    s1 = sth1 * r1;
  float tq2  = tq * tq;
  float cth2 = rsqrtf(1.f + tq2);
  float sth2 = tq * cth2;
  float u2   = 1.f + cth2, r2 = rsqrtf(u2 + u2);
  float c2   = u2 * r2,    s2 = sth2 * r2;
  A_ = c1 * c2; B_ = c1 * s2; C_ = s1 * c2; D_ = s1 * s2;
}

// tree-shaped product-state embedding (R9-verified); wire w's factor is
// broadcast from its Walsh lane.
__device__ __forceinline__ v2f embed_tree(float A_, float B_, float C_, float D_, int lane) {
  constexpr int LW[6] = {0x2A, 0x15, 0x01, 0x35, 0x3A, 0x3D};
  v2f f[6];
#pragma unroll
  for (int w = 0; w < 6; ++w) {
    float Aj = rl(A_, LW[w]), Bj = rl(B_, LW[w]);
    float Cj = rl(C_, LW[w]), Dj = rl(D_, LW[w]);
    bool bj = (lane >> w) & 1;
    f[w].x = bj ? Cj : Aj;
    f[w].y = bj ? Dj : -Bj;
  }
  v2f p01 = cmul(f[0], f[1]);
  v2f p23 = cmul(f[2], f[3]);
  v2f p45 = cmul(f[4], f[5]);
  return cmul(cmul(p01, p23), p45);
}

} // namespace

// ---- prep kernel (R7-verified): fused RZ*RY*RX row-0 -> d_ws ----
// Layout: Kw[circuit*12 + gate]  (circuit-major: one circuit = 192B chunk)
__global__ void qlstm_prep(const float* __restrict__ phi, float4* __restrict__ Kw) {
  int k = threadIdx.x;
  if (k < 72) {
    int g = k / 12, rem = k % 12, l = rem / 6, i = rem % 6;
    const float* w = phi + g*36 + l*18 + i*3;
    float sa, ca, sb, cb, sc, cc;
    sincosf(0.5f * w[0], &sa, &ca);
    sincosf(0.5f * w[1], &sb, &cb);
    sincosf(0.5f * w[2], &sc, &cc);
    float m00r =  cb*ca, m00i =  sb*sa;
    float m01r = -sb*ca, m01i = -cb*sa;
    float4 A;
    A.x = m00r*cc + m00i*sc;  A.y = m00i*cc - m00r*sc;
    A.z = m01r*cc + m01i*sc;  A.w = m01i*cc - m01r*sc;
    Kw[g*12 + rem] = A;
  }
}

__global__ __launch_bounds__(256, 2)
void qlstm_kernel(const float* __restrict__ x, const float* __restrict__ Wc,
                  const float* __restrict__ bc, const float4* __restrict__ Kw,
                  float* __restrict__ out)
{
  __shared__ float4 gates4[6];                 // per-wire (f,i,C,o), sigmoided
  __shared__ __align__(16) float h_s[8];

  const int tid   = threadIdx.x;
  const int wave  = tid >> 6;
  const int lane  = tid & 63;
  const int lane4 = lane << 2;
  const int b     = blockIdx.x;

  if (tid < 8) h_s[tid] = 0.f;

  // ---- coefficients -> SGPRs: readfirstlane forces wave-uniform address,
  // so these 24 loads compile to s_load_dwordx4 and live in SGPRs ----
  const int c1off = __builtin_amdgcn_readfirstlane(wave * 12);
  const int c2off = __builtin_amdgcn_readfirstlane((4 + (wave & 1)) * 12);
  float4 K1[12], K2[12];
#pragma unroll
  for (int i = 0; i < 12; ++i) K1[i] = Kw[c1off + i];
#pragma unroll
  for (int i = 0; i < 12; ++i) K2[i] = Kw[c2off + i];

  // ---- per-lane loop-invariants ----
  // gidx: wire owned by this lane's Walsh coefficient (-1 if none), R9-verified
  const int gidx = (lane == 0x2A) ? 0 : (lane == 0x15) ? 1 : (lane == 0x01) ? 2 :
                   (lane == 0x35) ? 3 : (lane == 0x3A) ? 4 : (lane == 0x3D) ? 5 : -1;
  const int jrow = (gidx >= 0) ? gidx : 0;

  float Wr[14];
#pragma unroll
  for (int k = 0; k < 14; ++k) Wr[k] = Wc[jrow*14 + k];
  const float bcj = bc[jrow];

  float sgn[6];
#pragma unroll
  for (int k = 0; k < 6; ++k) sgn[k] = ((lane >> k) & 1) ? -1.f : 1.f;
  float fs[9] = { sgn[0]*sgn[1], sgn[1], sgn[0],
                  sgn[2]*sgn[3], sgn[3], sgn[2],
                  sgn[4]*sgn[5], sgn[5], sgn[4] };

  // per-lane sign masks (gate order), circuit-independent (R5-verified)
  constexpr unsigned BM[2][6] = {
    {0x18,0x30,0x39,0x0C,0x26,0x33},
    {0x2A,0x15,0x01,0x35,0x3A,0x3D}};
  int pm[12];
#pragma unroll
  for (int l = 0; l < 2; ++l)
#pragma unroll
    for (int i = 0; i < 6; ++i)
      pm[l*6+i] = (__popc(lane & (int)BM[l][i]) & 1) << 31;

  float c_sc  = 0.f;   // cell state (meaningful at Walsh lanes), waves 0,1
  float hlast = 0.f;

  const float* xbase = x + (size_t)b * TSTEPS * 8;
  float4 xa = *(const float4*)(xbase);
  float4 xb = *(const float4*)(xbase + 4);

  __syncthreads();   // h_s init visible

  for (int t = 0; t < TSTEPS; ++t) {
    // ---- phase 1: X (valid at Walsh lanes), embed, own circuit ----
    float4 h4 = *(const float4*)&h_s[0];
    float2 h2 = *(const float2*)&h_s[4];
    float acc = bcj;
    acc = fmaf(xa.x, Wr[0],  acc); acc = fmaf(xa.y, Wr[1],  acc);
    acc = fmaf(xa.z, Wr[2],  acc); acc = fmaf(xa.w, Wr[3],  acc);
    acc = fmaf(xb.x, Wr[4],  acc); acc = fmaf(xb.y, Wr[5],  acc);
    acc = fmaf(xb.z, Wr[6],  acc); acc = fmaf(xb.w, Wr[7],  acc);
    acc = fmaf(h4.x, Wr[8],  acc); acc = fmaf(h4.y, Wr[9],  acc);
    acc = fmaf(h4.z, Wr[10], acc); acc = fmaf(h4.w, Wr[11], acc);
    acc = fmaf(h2.x, Wr[12], acc); acc = fmaf(h2.y, Wr[13], acc);
    float Xj = 1.f - 2.f / (1.f + __expf(acc));

    // prefetch next x
    int tn = (t + 1 < TSTEPS) ? (t + 1) : t;
    float4 xa_n = *(const float4*)(xbase + (size_t)tn * 8);
    float4 xb_n = *(const float4*)(xbase + (size_t)tn * 8 + 4);

    float A_, B_, C_, D_;
    trig(Xj, A_, B_, C_, D_);
    v2f s = embed_tree(A_, B_, C_, D_, lane);
    chain12(s, K1, pm, lane4);
    float p   = expv(s, fs, lane4);
    float sgv = sigf(p);
    if (gidx >= 0) ((float*)&gates4[gidx])[wave] = sgv;
    __syncthreads();

    // ---- phase 2: cell update + h (wave0), y (wave1) ----
    if (wave < 2) {
      float4 g4 = gates4[jrow];                  // (f,i,C,o) for wire jrow
      float cn  = fmaf(g4.x, c_sc, g4.y * g4.z);
      c_sc = cn;
      float resc = g4.w * tanh_fast(cn);
      float A2, B2, C2, D2;
      trig(resc, A2, B2, C2, D2);
      v2f s2 = embed_tree(A2, B2, C2, D2, lane);
      chain12(s2, K2, pm, lane4);
      float p2v = expv(s2, fs, lane4);
      if (wave == 0) {
        if (gidx >= 0) h_s[gidx] = p2v;
        hlast = p2v;
      } else if (gidx >= 0) {
        out[((size_t)b * TSTEPS + t) * 6 + gidx] = p2v;
      }
    }
    xa = xa_n; xb = xb_n;
    __syncthreads();
  }

  // ---- final c, h (wave 0, Walsh lanes) ----
  if (wave == 0 && gidx >= 0) {
    size_t cbase = (size_t)BATCH * TSTEPS * 6;
    out[cbase + (size_t)b * 6 + gidx] = c_sc;
    out[cbase + (size_t)BATCH * 6 + (size_t)b * 6 + gidx] = hlast;
  }
}

extern "C" void kernel_launch(void* const* d_in, const int* in_sizes, int n_in,
                              void* d_out, int out_size, void* d_ws, size_t ws_size,
                              hipStream_t stream) {
  const float* x   = (const float*)d_in[0];
  const float* phi = (const float*)d_in[1];
  const float* Wc  = (const float*)d_in[2];
  const float* bc  = (const float*)d_in[3];
  float* out = (float*)d_out;
  float4* Kw = (float4*)d_ws;   // 72 float4 = 1152 B
  (void)in_sizes; (void)n_in; (void)out_size; (void)ws_size;
  hipLaunchKernelGGL(qlstm_prep, dim3(1), dim3(128), 0, stream, phi, Kw);
  hipLaunchKernelGGL(qlstm_kernel, dim3(BATCH), dim3(256), 0, stream,
                     x, Wc, bc, Kw, out);
}